// Round 17
// baseline (119.039 us; speedup 1.0000x reference)
//
#include <hip/hip_runtime.h>
#include <hip/hip_bf16.h>
#include <math.h>

namespace {

constexpr int SEQ    = 1024;
constexpr int DMODEL = 1024;
constexpr int DINNER = 2048;
constexpr int DSTATE = 16;
constexpr int DTRANK = 64;
constexpr int XPW    = 96;
constexpr int XPWP   = 128;

typedef __attribute__((ext_vector_type(8))) short short8;
typedef __attribute__((ext_vector_type(4))) short short4_t;
typedef __attribute__((ext_vector_type(4))) float floatx4;

#define GLB __attribute__((address_space(1)))
#define LDSAS __attribute__((address_space(3)))

__device__ __forceinline__ float siluf(float x) { return x / (1.f + __expf(-x)); }

__device__ __forceinline__ unsigned short f2b(float f) {
    __hip_bfloat16 h = __float2bfloat16(f);
    return *reinterpret_cast<unsigned short*>(&h);
}
__device__ __forceinline__ float b2f(unsigned short u) {
    union { unsigned int i; float f; } v; v.i = (unsigned int)u << 16; return v.f;
}

// ---------------- fused bf16 cast of x + all weights ----------------
constexpr size_t N_XB   = (size_t)SEQ * DMODEL;
constexpr size_t N_WIN  = (size_t)2 * DINNER * DMODEL;
constexpr size_t N_WXP  = (size_t)XPWP * DINNER;
constexpr size_t N_WDT  = (size_t)DINNER * DTRANK;
constexpr size_t N_WOUT = (size_t)DMODEL * DINNER;
constexpr size_t CO1 = N_XB, CO2 = CO1 + N_WIN, CO3 = CO2 + N_WXP,
                 CO4 = CO3 + N_WDT, CO5 = CO4 + N_WOUT;

__global__ __launch_bounds__(256)
void cast_all(const float* __restrict__ x, const float* __restrict__ Win,
              const float* __restrict__ Wxp, const float* __restrict__ Wdt,
              const float* __restrict__ Wout, unsigned short* __restrict__ dst)
{
    size_t i = ((size_t)blockIdx.x * 256 + threadIdx.x) * 8;
    if (i >= CO5) return;
    const float* src; size_t si;
    if (i < CO1)      { src = x;   si = i; }
    else if (i < CO2) { src = Win; si = i - CO1; }
    else if (i < CO3) {
        size_t j = i - CO2, row = j / DINNER;
        if (row >= XPW) { short8 z = {0,0,0,0,0,0,0,0};
                          *reinterpret_cast<short8*>(&dst[i]) = z; return; }
        src = Wxp; si = j;
    }
    else if (i < CO4) { src = Wdt;  si = i - CO3; }
    else              { src = Wout; si = i - CO4; }
    float4 a = *reinterpret_cast<const float4*>(&src[si]);
    float4 b = *reinterpret_cast<const float4*>(&src[si + 4]);
    short8 o;
    o[0]=(short)f2b(a.x); o[1]=(short)f2b(a.y); o[2]=(short)f2b(a.z); o[3]=(short)f2b(a.w);
    o[4]=(short)f2b(b.x); o[5]=(short)f2b(b.y); o[6]=(short)f2b(b.z); o[7]=(short)f2b(b.w);
    *reinterpret_cast<short8*>(&dst[i]) = o;
}

// ------------- bf16 MFMA GEMM, BK=64, counted-vmcnt 2-deep pipeline, XCD swizzle ---------
// C[M][N] = A[M][K] @ B[N][K]^T.  1D grid in x (nbx columns), split-K in z.
// TILE=0: 64x128 block, wave 32x64 (MR2xNR4), 6 loads/stage, 48 KB LDS.
// TILE=1: 128x128 block, wave 64x64 (MR4xNR4), 8 loads/stage, 64 KB LDS —
//         8 ds_read : 32 MFMA per wave-iter (3x better DS:MFMA ratio).
// RACE-HARDENED (r16): every s_barrier fenced with sched_barrier(0) on BOTH sides —
// stage()'s LDS-writing loads cannot hoist above barrier-2, ds_reads cannot hoist
// above barrier-1 (raw s_barrier is not a compiler memory fence; r15 lesson).
// Counted vmcnt: wait only for current buffer's loads; next stage stays in flight.
// XOR swizzle (u ^ row&7) on both staging source column and ds_read (rule #21).
// EPI: 0 = f32 store, 1 = softplus(v+bias[n]) f32, 2 = bf16 store (to gz base),
//      3 = split xi(f32)/silu->gz(bf16).
template<int EPI, int TILE>
__global__ __launch_bounds__(256)
void gemm_mfma(const unsigned short* __restrict__ A, int lda,
               const unsigned short* __restrict__ B, int ldb,
               float* __restrict__ C, int ldc, size_t czstride,
               const float* __restrict__ bias, int Ksub, int nbx,
               unsigned short* __restrict__ gz)
{
    constexpr int BM = TILE ? 128 : 64;
    constexpr int BN = 128, BK = 64;
    constexpr int MR = TILE ? 4 : 2, NR = 4;
    constexpr int WM = TILE ? 64 : 32;     // wave M extent
    constexpr int AR = BM / 32;            // A staging rounds (2 or 4)
    __shared__ unsigned short Alds[2][BM * BK];
    __shared__ unsigned short Blds[2][BN * BK];

    // bijective XCD-chunk swizzle (all launches have gridDim.x % 8 == 0)
    const int nwg = gridDim.x;
    int id = blockIdx.x;
    int wg = ((nwg & 7) == 0) ? (id & 7) * (nwg >> 3) + (id >> 3) : id;
    const int bx = wg % nbx, by = wg / nbx;

    const int tid  = threadIdx.x;
    const int lane = tid & 63;
    const int wv   = tid >> 6;
    const int wm   = wv >> 1, wn = wv & 1;
    const int fr   = lane & 15;
    const int kg   = lane >> 4;
    const int m0   = by * BM;
    const int n0   = bx * BN;
    const int kb   = blockIdx.z * Ksub;
    float* Cz = C + (size_t)blockIdx.z * czstride;
    unsigned short* Gz = gz + (size_t)blockIdx.z * czstride;   // EPI==2 base

    // staging map: per round, 256 threads cover 32 rows x 64 cols (8 units of 16B)
    const int srow = tid >> 3;        // 0..31
    const int uslt = tid & 7;         // LDS 16B-unit slot
    const int fsw  = fr & 7;          // read-side XOR key

    floatx4 acc[MR][NR];
#pragma unroll
    for (int mi = 0; mi < MR; ++mi)
#pragma unroll
        for (int ni = 0; ni < NR; ++ni)
            acc[mi][ni] = (floatx4){0.f, 0.f, 0.f, 0.f};

    auto stage = [&](int buf, int k0) {   // AR+4 gload_lds per thread
#pragma unroll
        for (int r = 0; r < AR; ++r) {
            int row = r * 32 + srow;
            int gc  = k0 + ((uslt ^ (row & 7)) << 3);   // inverse-swizzled source
            __builtin_amdgcn_global_load_lds(
                (const GLB unsigned int*)&A[(size_t)(m0 + row) * lda + gc],
                (LDSAS unsigned int*)&Alds[buf][r * 2048 + tid * 8], 16, 0, 0);
        }
#pragma unroll
        for (int r = 0; r < 4; ++r) {
            int row = r * 32 + srow;
            int gc  = k0 + ((uslt ^ (row & 7)) << 3);
            __builtin_amdgcn_global_load_lds(
                (const GLB unsigned int*)&B[(size_t)(n0 + row) * ldb + gc],
                (LDSAS unsigned int*)&Blds[buf][r * 2048 + tid * 8], 16, 0, 0);
        }
    };

    const int nt = Ksub / BK;
    stage(0, kb);
    if (nt > 1) stage(1, kb + BK);      // 2-deep prologue
    int cur = 0;
    for (int t = 0; t < nt; ++t) {
        if (t + 1 < nt) {
            if constexpr (TILE)
                asm volatile("s_waitcnt vmcnt(8)" ::: "memory");  // cur's 8 done
            else
                asm volatile("s_waitcnt vmcnt(6)" ::: "memory");  // cur's 6 done
        } else {
            asm volatile("s_waitcnt vmcnt(0)" ::: "memory");      // tail: drain all
        }
        __builtin_amdgcn_sched_barrier(0);
        __builtin_amdgcn_s_barrier();                          // cur buffer valid for all
        __builtin_amdgcn_sched_barrier(0);                     // reads stay BELOW barrier

        short8 af[2][MR], bf[2][NR];
#pragma unroll
        for (int kk = 0; kk < 2; ++kk) {
#pragma unroll
            for (int mi = 0; mi < MR; ++mi) {
                int row = wm * WM + mi * 16 + fr;
                int u   = (kk * 4 + kg) ^ fsw;
                af[kk][mi] = *reinterpret_cast<const short8*>(
                    &Alds[cur][row * BK + u * 8]);
            }
#pragma unroll
            for (int ni = 0; ni < NR; ++ni) {
                int row = wn * 64 + ni * 16 + fr;
                int u   = (kk * 4 + kg) ^ fsw;
                bf[kk][ni] = *reinterpret_cast<const short8*>(
                    &Blds[cur][row * BK + u * 8]);
            }
        }
#pragma unroll
        for (int kk = 0; kk < 2; ++kk)
#pragma unroll
            for (int mi = 0; mi < MR; ++mi)
#pragma unroll
                for (int ni = 0; ni < NR; ++ni)
                    acc[mi][ni] = __builtin_amdgcn_mfma_f32_16x16x32_bf16(
                        af[kk][mi], bf[kk][ni], acc[mi][ni], 0, 0, 0);

        __builtin_amdgcn_sched_barrier(0);                     // reads/MFMAs stay ABOVE
        __builtin_amdgcn_s_barrier();                          // all waves done reading cur
        __builtin_amdgcn_sched_barrier(0);                     // stage stays BELOW barrier
        if (t + 2 < nt) stage(cur, kb + (t + 2) * BK);         // safe to overwrite cur
        cur ^= 1;
    }

#pragma unroll
    for (int mi = 0; mi < MR; ++mi)
#pragma unroll
        for (int ni = 0; ni < NR; ++ni)
#pragma unroll
            for (int r = 0; r < 4; ++r) {
                int row = m0 + wm * WM + mi * 16 + kg * 4 + r;
                int col = n0 + wn * 64 + ni * 16 + fr;
                float v = acc[mi][ni][r];
                if constexpr (EPI == 1) {
                    v += bias[col];
                    v = (v > 20.f) ? v : log1pf(__expf(v));
                    Cz[(size_t)row * ldc + col] = v;
                } else if constexpr (EPI == 2) {
                    Gz[(size_t)row * ldc + col] = f2b(v);             // bf16 partial
                } else if constexpr (EPI == 3) {
                    if (col < DINNER)
                        Cz[(size_t)row * ldc + col] = v;              // xi (f32)
                    else
                        gz[(size_t)row * DINNER + col - DINNER] = f2b(siluf(v));
                } else {
                    Cz[(size_t)row * ldc + col] = v;
                }
            }
}

// sum 16 split-K partials -> xdbl f32 + bf16
__global__ __launch_bounds__(256)
void combine_xdbl(const float* __restrict__ xp, float* __restrict__ xf,
                  unsigned short* __restrict__ xb)
{
    int i = (blockIdx.x * 256 + threadIdx.x) * 4;   // over SEQ*XPWP
    constexpr size_t SL = (size_t)SEQ * XPWP;
    float4 s{0.f, 0.f, 0.f, 0.f};
#pragma unroll
    for (int z = 0; z < 16; ++z) {
        float4 p = *reinterpret_cast<const float4*>(&xp[z * SL + i]);
        s.x += p.x; s.y += p.y; s.z += p.z; s.w += p.w;
    }
    *reinterpret_cast<float4*>(&xf[i]) = s;
    short4_t o; o[0]=(short)f2b(s.x); o[1]=(short)f2b(s.y);
                o[2]=(short)f2b(s.z); o[3]=(short)f2b(s.w);
    *reinterpret_cast<short4_t*>(&xb[i]) = o;
}

// sum 4 bf16 split-K partials -> final f32 out
__global__ __launch_bounds__(256)
void combine_out(const unsigned short* __restrict__ op, float* __restrict__ out)
{
    int i = (blockIdx.x * 256 + threadIdx.x) * 4;   // over SEQ*DMODEL
    constexpr size_t SL = (size_t)SEQ * DMODEL;
    float4 s{0.f, 0.f, 0.f, 0.f};
#pragma unroll
    for (int z = 0; z < 4; ++z) {
        short4_t p = *reinterpret_cast<const short4_t*>(&op[z * SL + i]);
        s.x += b2f((unsigned short)p[0]);
        s.y += b2f((unsigned short)p[1]);
        s.z += b2f((unsigned short)p[2]);
        s.w += b2f((unsigned short)p[3]);
    }
    *reinterpret_cast<float4*>(&out[i]) = s;
}

// causal depthwise conv (width 4) + bias + silu; xi f32 in, xic bf16 out.
__global__ __launch_bounds__(256)
void conv_silu(const float* __restrict__ xi,
               const float* __restrict__ conv_w,
               const float* __restrict__ conv_b,
               unsigned short* __restrict__ xic)
{
    int idx = blockIdx.x * 256 + threadIdx.x;    // over (SEQ/4)*DINNER
    int l0 = (idx / DINNER) * 4;
    int d  = idx % DINNER;
    float4 w = *reinterpret_cast<const float4*>(&conv_w[d * 4]);
    float cb = conv_b[d];
    float v[7];
#pragma unroll
    for (int k = 0; k < 7; ++k) {
        int ls = l0 - 3 + k;
        v[k] = (ls >= 0) ? xi[(size_t)ls * DINNER + d] : 0.f;
    }
#pragma unroll
    for (int j = 0; j < 4; ++j) {
        float acc = cb;
        acc = fmaf(v[j],     w.x, acc);
        acc = fmaf(v[j + 1], w.y, acc);
        acc = fmaf(v[j + 2], w.z, acc);
        acc = fmaf(v[j + 3], w.w, acc);
        xic[(size_t)(l0 + j) * DINNER + d] = f2b(siluf(acc));
    }
}

// ---------------- chunk-parallel selective scan, n-in-registers, barrier-free ----
__global__ __launch_bounds__(256)
void scan_pass1(const float* __restrict__ delta,
                const unsigned short* __restrict__ xic,
                const float* __restrict__ xdbl,     // f32 [SEQ][128], B at 64
                const float* __restrict__ A_log,
                float* __restrict__ sdlbuf,         // [NC][DINNER]
                float* __restrict__ Sbuf, int CH)   // [NC][16][DINNER]
{
    const int tid = threadIdx.x;
    const int d   = blockIdx.x * 256 + tid;
    const int c   = blockIdx.y;
    const int tb  = c * CH;

    float An[16], h[16];
#pragma unroll
    for (int n = 0; n < 16; ++n) {
        An[n] = -__expf(A_log[(size_t)d * 16 + n]);
        h[n]  = 0.f;
    }
    float sdl = 0.f;

#pragma unroll 4
    for (int t = tb; t < tb + CH; ++t) {
        float dl = delta[(size_t)t * DINNER + d];
        float xv = b2f(xic[(size_t)t * DINNER + d]);
        const float4* R = reinterpret_cast<const float4*>(&xdbl[(size_t)t * XPWP + DTRANK]);
        float4 B0 = R[0], B1 = R[1], B2 = R[2], B3 = R[3];
        float Bv[16] = {B0.x,B0.y,B0.z,B0.w, B1.x,B1.y,B1.z,B1.w,
                        B2.x,B2.y,B2.z,B2.w, B3.x,B3.y,B3.z,B3.w};
        float t1 = dl * xv;
        sdl += dl;
#pragma unroll
        for (int n = 0; n < 16; ++n) {
            float a = __expf(dl * An[n]);
            h[n] = fmaf(a, h[n], t1 * Bv[n]);
        }
    }
    sdlbuf[(size_t)c * DINNER + d] = sdl;
#pragma unroll
    for (int n = 0; n < 16; ++n)
        Sbuf[((size_t)c * 16 + n) * DINNER + d] = h[n];
}

// serial scan over chunk summaries; recomputes P = exp(sdl*A); Hin in place over Sbuf
__global__ __launch_bounds__(64)
void scan_pass2(const float* __restrict__ sdlbuf,
                const float* __restrict__ A_log,
                float* __restrict__ Sbuf, int NCr)
{
    int idx = blockIdx.x * 64 + threadIdx.x;        // n*2048 + d
    int n = idx >> 11, d = idx & 2047;
    const float Aneg = -__expf(A_log[(size_t)d * 16 + n]);
    float h = 0.f;
    for (int c = 0; c < NCr; ++c) {
        size_t o = (size_t)c * (DINNER * DSTATE) + idx;
        float p = __expf(sdlbuf[(size_t)c * DINNER + d] * Aneg);
        float s = Sbuf[o];
        Sbuf[o] = h;
        h = fmaf(p, h, s);
    }
}

__global__ __launch_bounds__(256)
void scan_pass3(const float* __restrict__ delta,
                const unsigned short* __restrict__ xic,
                const float* __restrict__ xdbl,     // B at 64, C at 80
                const float* __restrict__ A_log,
                const float* __restrict__ D_skip,
                const unsigned short* __restrict__ gz,   // silu(z) bf16
                const float* __restrict__ Hin,           // [c][n][d] (= Sbuf)
                unsigned short* __restrict__ yfin, int CH)
{
    const int tid = threadIdx.x;
    const int d   = blockIdx.x * 256 + tid;
    const int c   = blockIdx.y;
    const int tb  = c * CH;

    float An[16], h[16];
#pragma unroll
    for (int n = 0; n < 16; ++n) {
        An[n] = -__expf(A_log[(size_t)d * 16 + n]);
        h[n]  = Hin[((size_t)c * 16 + n) * DINNER + d];
    }
    const float Dsk = D_skip[d];

#pragma unroll 4
    for (int t = tb; t < tb + CH; ++t) {
        float dl = delta[(size_t)t * DINNER + d];
        float xv = b2f(xic[(size_t)t * DINNER + d]);
        float zv = b2f(gz[(size_t)t * DINNER + d]);
        const float4* R = reinterpret_cast<const float4*>(&xdbl[(size_t)t * XPWP + DTRANK]);
        float4 B0 = R[0], B1 = R[1], B2 = R[2], B3 = R[3];
        float4 C0 = R[4], C1 = R[5], C2 = R[6], C3 = R[7];
        float Bv[16] = {B0.x,B0.y,B0.z,B0.w, B1.x,B1.y,B1.z,B1.w,
                        B2.x,B2.y,B2.z,B2.w, B3.x,B3.y,B3.z,B3.w};
        float Cv[16] = {C0.x,C0.y,C0.z,C0.w, C1.x,C1.y,C1.z,C1.w,
                        C2.x,C2.y,C2.z,C2.w, C3.x,C3.y,C3.z,C3.w};
        float t1 = dl * xv;
        float y = 0.f;
#pragma unroll
        for (int n = 0; n < 16; ++n) {
            float a = __expf(dl * An[n]);
            h[n] = fmaf(a, h[n], t1 * Bv[n]);
            y = fmaf(h[n], Cv[n], y);
        }
        float yv = fmaf(xv, Dsk, y) * zv;
        yfin[(size_t)t * DINNER + d] = f2b(yv);
    }
}

}  // namespace

extern "C" void kernel_launch(void* const* d_in, const int* in_sizes, int n_in,
                              void* d_out, int out_size, void* d_ws, size_t ws_size,
                              hipStream_t stream)
{
    (void)in_sizes; (void)n_in; (void)out_size;

    const float* x       = (const float*)d_in[0];
    const float* W_in    = (const float*)d_in[1];
    const float* conv_w  = (const float*)d_in[2];
    const float* conv_b  = (const float*)d_in[3];
    const float* W_xproj = (const float*)d_in[4];
    const float* W_dt    = (const float*)d_in[5];
    const float* b_dt    = (const float*)d_in[6];
    const float* A_log   = (const float*)d_in[7];
    const float* D_skip  = (const float*)d_in[8];
    const float* W_out   = (const float*)d_in[9];
    float* out = (float*)d_out;

    // ---- workspace budget / NC select ----
    const size_t F32_FIXED = 2 * (size_t)SEQ * DINNER        // xi_f, delta
                           + (size_t)SEQ * XPWP              // xdbl_f
                           + 16 * (size_t)SEQ * XPWP;        // xpart (16 slabs)
    const size_t BF16_SHORTS = CO5 + 3 * (size_t)SEQ * DINNER + (size_t)SEQ * XPWP
                             + 4 * (size_t)SEQ * DMODEL;     // + opart bf16
    auto need = [&](int nc) {
        return (F32_FIXED + (size_t)nc * DINNER + (size_t)nc * DINNER * DSTATE) * 4
             + BF16_SHORTS * 2;
    };
    int NC = 64;
    if (need(64) > ws_size) NC = 32;
    if (need(32) > ws_size) NC = 16;
    const int CH = SEQ / NC;

    // ---- workspace carve (no aliasing) ----
    float* ws     = (float*)d_ws;
    float* xi_f   = ws;                                    // SEQ*2048
    float* delta  = xi_f   + (size_t)SEQ * DINNER;         // SEQ*2048
    float* xdbl_f = delta  + (size_t)SEQ * DINNER;         // SEQ*128
    float* xpart  = xdbl_f + (size_t)SEQ * XPWP;           // 16*SEQ*128
    float* sdlbuf = xpart  + 16 * (size_t)SEQ * XPWP;      // NC*2048
    float* Sbuf   = sdlbuf + (size_t)NC * DINNER;          // NC*16*2048
    unsigned short* x_b    = (unsigned short*)(Sbuf + (size_t)NC * DINNER * DSTATE);
    unsigned short* Win_b  = x_b + CO1;
    unsigned short* Wxp_b  = x_b + CO2;
    unsigned short* Wdt_b  = x_b + CO3;
    unsigned short* Wout_b = x_b + CO4;
    unsigned short* xic_b  = x_b + CO5;
    unsigned short* yfin_b = xic_b  + (size_t)SEQ * DINNER;
    unsigned short* gz_b   = yfin_b + (size_t)SEQ * DINNER;
    unsigned short* xdbl_b = gz_b   + (size_t)SEQ * DINNER;
    unsigned short* opart_b = xdbl_b + (size_t)SEQ * XPWP;  // 4*SEQ*1024 bf16

    // 0) all bf16 casts
    cast_all<<<(int)((CO5 / 8 + 255) / 256), 256, 0, stream>>>(
        x, W_in, W_xproj, W_dt, W_out, x_b);

    // 1) xz = x @ W_in^T (1024 x 4096, K=1024): 128x128 tile, 32x8 = 256 blocks
    //    epilogue: cols<2048 -> xi_f (f32), cols>=2048 -> gz = silu(z) bf16
    gemm_mfma<3, 1><<<dim3(256, 1, 1), 256, 0, stream>>>(
        x_b, DMODEL, Win_b, DMODEL, xi_f, DINNER, 0, nullptr, DMODEL, 32, gz_b);

    // 2) conv + silu -> xic (bf16), 4 rows/thread
    conv_silu<<<(SEQ / 4) * DINNER / 256, 256, 0, stream>>>(xi_f, conv_w, conv_b, xic_b);

    // 3) x_dbl = xic @ W_xproj^T, split-K=16 (1024 x 128pad, K=2048): 16 x 16z
    gemm_mfma<0, 0><<<dim3(16, 1, 16), 256, 0, stream>>>(
        xic_b, DINNER, Wxp_b, DINNER, xpart, XPWP, (size_t)SEQ * XPWP,
        nullptr, DINNER / 16, 1, nullptr);
    combine_xdbl<<<(SEQ * XPWP) / 1024, 256, 0, stream>>>(xpart, xdbl_f, xdbl_b);

    // 4) delta = softplus(dt @ W_dt^T + b_dt) (1024 x 2048, K=64): 16x16 = 256 blocks
    gemm_mfma<1, 0><<<dim3(256, 1, 1), 256, 0, stream>>>(
        xdbl_b, XPWP, Wdt_b, DTRANK, delta, DINNER, 0, b_dt, DTRANK, 16, nullptr);

    // 5) chunk-parallel selective scan + gate fusion (barrier-free passes)
    scan_pass1<<<dim3(DINNER / 256, NC), 256, 0, stream>>>(
        delta, xic_b, xdbl_f, A_log, sdlbuf, Sbuf, CH);
    scan_pass2<<<(DINNER * DSTATE) / 64, 64, 0, stream>>>(sdlbuf, A_log, Sbuf, NC);
    scan_pass3<<<dim3(DINNER / 256, NC), 256, 0, stream>>>(
        delta, xic_b, xdbl_f, A_log, D_skip, gz_b, Sbuf, yfin_b, CH);

    // 6) out = y @ W_out^T, 128x128 tile, split-K=4, bf16 partials: 64 x 4z blocks
    gemm_mfma<2, 1><<<dim3(64, 1, 4), 256, 0, stream>>>(
        yfin_b, DINNER, Wout_b, DINNER, nullptr, DMODEL, (size_t)SEQ * DMODEL,
        nullptr, DINNER / 4, 8, opart_b);
    combine_out<<<(SEQ * DMODEL) / 1024, 256, 0, stream>>>(opart_b, out);
}

// Round 18
// 110.453 us; speedup vs baseline: 1.0777x; 1.0777x over previous
//
#include <hip/hip_runtime.h>
#include <hip/hip_bf16.h>
#include <math.h>

namespace {

constexpr int SEQ    = 1024;
constexpr int DMODEL = 1024;
constexpr int DINNER = 2048;
constexpr int DSTATE = 16;
constexpr int DTRANK = 64;
constexpr int XPW    = 96;
constexpr int XPWP   = 128;

typedef __attribute__((ext_vector_type(8))) short short8;
typedef __attribute__((ext_vector_type(4))) short short4_t;
typedef __attribute__((ext_vector_type(4))) float floatx4;

#define GLB __attribute__((address_space(1)))
#define LDSAS __attribute__((address_space(3)))

__device__ __forceinline__ float siluf(float x) { return x / (1.f + __expf(-x)); }

__device__ __forceinline__ unsigned short f2b(float f) {
    __hip_bfloat16 h = __float2bfloat16(f);
    return *reinterpret_cast<unsigned short*>(&h);
}
__device__ __forceinline__ float b2f(unsigned short u) {
    union { unsigned int i; float f; } v; v.i = (unsigned int)u << 16; return v.f;
}

// ---------------- fused bf16 cast of x + all weights ----------------
constexpr size_t N_XB   = (size_t)SEQ * DMODEL;
constexpr size_t N_WIN  = (size_t)2 * DINNER * DMODEL;
constexpr size_t N_WXP  = (size_t)XPWP * DINNER;
constexpr size_t N_WDT  = (size_t)DINNER * DTRANK;
constexpr size_t N_WOUT = (size_t)DMODEL * DINNER;
constexpr size_t CO1 = N_XB, CO2 = CO1 + N_WIN, CO3 = CO2 + N_WXP,
                 CO4 = CO3 + N_WDT, CO5 = CO4 + N_WOUT;

__global__ __launch_bounds__(256)
void cast_all(const float* __restrict__ x, const float* __restrict__ Win,
              const float* __restrict__ Wxp, const float* __restrict__ Wdt,
              const float* __restrict__ Wout, unsigned short* __restrict__ dst)
{
    size_t i = ((size_t)blockIdx.x * 256 + threadIdx.x) * 8;
    if (i >= CO5) return;
    const float* src; size_t si;
    if (i < CO1)      { src = x;   si = i; }
    else if (i < CO2) { src = Win; si = i - CO1; }
    else if (i < CO3) {
        size_t j = i - CO2, row = j / DINNER;
        if (row >= XPW) { short8 z = {0,0,0,0,0,0,0,0};
                          *reinterpret_cast<short8*>(&dst[i]) = z; return; }
        src = Wxp; si = j;
    }
    else if (i < CO4) { src = Wdt;  si = i - CO3; }
    else              { src = Wout; si = i - CO4; }
    float4 a = *reinterpret_cast<const float4*>(&src[si]);
    float4 b = *reinterpret_cast<const float4*>(&src[si + 4]);
    short8 o;
    o[0]=(short)f2b(a.x); o[1]=(short)f2b(a.y); o[2]=(short)f2b(a.z); o[3]=(short)f2b(a.w);
    o[4]=(short)f2b(b.x); o[5]=(short)f2b(b.y); o[6]=(short)f2b(b.z); o[7]=(short)f2b(b.w);
    *reinterpret_cast<short8*>(&dst[i]) = o;
}

// ------------- bf16 MFMA GEMM, 64x128 tile, BK=64, counted-vmcnt 2-deep pipeline ----------
// C[M][N] = A[M][K] @ B[N][K]^T.  1D grid in x (nbx columns), split-K in z.
// RACE-HARDENED: every s_barrier is fenced with sched_barrier(0) on BOTH sides, so
// the scheduler cannot hoist stage()'s LDS-writing loads above barrier-2 nor hoist
// ds_reads above barrier-1 (raw s_barrier is not a compiler memory fence — r15 race).
// Counted vmcnt: wait only for current buffer's 6 loads; next stage stays in flight.
// XOR swizzle (u ^ row&7) on both staging source column and ds_read (rule #21).
// EPI: 0 = f32 store, 1 = softplus(v+bias[n]) f32, 2 = bf16 store (to gz base),
//      3 = split xi(f32)/silu->gz(bf16).
template<int EPI>
__global__ __launch_bounds__(256)
void gemm_mfma(const unsigned short* __restrict__ A, int lda,
               const unsigned short* __restrict__ B, int ldb,
               float* __restrict__ C, int ldc, size_t czstride,
               const float* __restrict__ bias, int Ksub, int nbx,
               unsigned short* __restrict__ gz)
{
    constexpr int BM = 64, BN = 128, BK = 64, MR = 2, NR = 4;
    __shared__ unsigned short Alds[2][BM * BK];   // 16 KB
    __shared__ unsigned short Blds[2][BN * BK];   // 32 KB

    // bijective XCD-chunk swizzle (all launches have gridDim.x % 8 == 0)
    const int nwg = gridDim.x;
    int id = blockIdx.x;
    int wg = ((nwg & 7) == 0) ? (id & 7) * (nwg >> 3) + (id >> 3) : id;
    const int bx = wg % nbx, by = wg / nbx;

    const int tid  = threadIdx.x;
    const int lane = tid & 63;
    const int wv   = tid >> 6;
    const int wm   = wv >> 1, wn = wv & 1;
    const int fr   = lane & 15;
    const int kg   = lane >> 4;
    const int m0   = by * BM;
    const int n0   = bx * BN;
    const int kb   = blockIdx.z * Ksub;
    float* Cz = C + (size_t)blockIdx.z * czstride;
    unsigned short* Gz = gz + (size_t)blockIdx.z * czstride;   // EPI==2 base

    // staging map: per call, 256 threads cover 32 rows x 64 cols (8 units of 16B)
    const int srow = tid >> 3;        // 0..31
    const int uslt = tid & 7;         // LDS 16B-unit slot
    const int fsw  = fr & 7;          // read-side XOR key

    floatx4 acc[MR][NR];
#pragma unroll
    for (int mi = 0; mi < MR; ++mi)
#pragma unroll
        for (int ni = 0; ni < NR; ++ni)
            acc[mi][ni] = (floatx4){0.f, 0.f, 0.f, 0.f};

    auto stage = [&](int buf, int k0) {   // 6 gload_lds per thread
#pragma unroll
        for (int r = 0; r < 2; ++r) {
            int row = r * 32 + srow;
            int gc  = k0 + ((uslt ^ (row & 7)) << 3);   // inverse-swizzled source
            __builtin_amdgcn_global_load_lds(
                (const GLB unsigned int*)&A[(size_t)(m0 + row) * lda + gc],
                (LDSAS unsigned int*)&Alds[buf][r * 2048 + tid * 8], 16, 0, 0);
        }
#pragma unroll
        for (int r = 0; r < 4; ++r) {
            int row = r * 32 + srow;
            int gc  = k0 + ((uslt ^ (row & 7)) << 3);
            __builtin_amdgcn_global_load_lds(
                (const GLB unsigned int*)&B[(size_t)(n0 + row) * ldb + gc],
                (LDSAS unsigned int*)&Blds[buf][r * 2048 + tid * 8], 16, 0, 0);
        }
    };

    const int nt = Ksub / BK;
    stage(0, kb);
    if (nt > 1) stage(1, kb + BK);      // 2-deep prologue
    int cur = 0;
    for (int t = 0; t < nt; ++t) {
        if (t + 1 < nt) {
            asm volatile("s_waitcnt vmcnt(6)" ::: "memory");   // cur's 6 done; next in flight
        } else {
            asm volatile("s_waitcnt vmcnt(0)" ::: "memory");   // tail: drain all
        }
        __builtin_amdgcn_sched_barrier(0);
        __builtin_amdgcn_s_barrier();                          // cur buffer valid for all
        __builtin_amdgcn_sched_barrier(0);                     // reads stay BELOW barrier

        short8 af[2][MR], bf[2][NR];
#pragma unroll
        for (int kk = 0; kk < 2; ++kk) {
#pragma unroll
            for (int mi = 0; mi < MR; ++mi) {
                int row = wm * 32 + mi * 16 + fr;
                int u   = (kk * 4 + kg) ^ fsw;
                af[kk][mi] = *reinterpret_cast<const short8*>(
                    &Alds[cur][row * BK + u * 8]);
            }
#pragma unroll
            for (int ni = 0; ni < NR; ++ni) {
                int row = wn * 64 + ni * 16 + fr;
                int u   = (kk * 4 + kg) ^ fsw;
                bf[kk][ni] = *reinterpret_cast<const short8*>(
                    &Blds[cur][row * BK + u * 8]);
            }
        }
#pragma unroll
        for (int kk = 0; kk < 2; ++kk)
#pragma unroll
            for (int mi = 0; mi < MR; ++mi)
#pragma unroll
                for (int ni = 0; ni < NR; ++ni)
                    acc[mi][ni] = __builtin_amdgcn_mfma_f32_16x16x32_bf16(
                        af[kk][mi], bf[kk][ni], acc[mi][ni], 0, 0, 0);

        __builtin_amdgcn_sched_barrier(0);                     // reads/MFMAs stay ABOVE
        __builtin_amdgcn_s_barrier();                          // all waves done reading cur
        __builtin_amdgcn_sched_barrier(0);                     // stage stays BELOW barrier
        if (t + 2 < nt) stage(cur, kb + (t + 2) * BK);         // safe to overwrite cur
        cur ^= 1;
    }

#pragma unroll
    for (int mi = 0; mi < MR; ++mi)
#pragma unroll
        for (int ni = 0; ni < NR; ++ni)
#pragma unroll
            for (int r = 0; r < 4; ++r) {
                int row = m0 + wm * 32 + mi * 16 + kg * 4 + r;
                int col = n0 + wn * 64 + ni * 16 + fr;
                float v = acc[mi][ni][r];
                if constexpr (EPI == 1) {
                    v += bias[col];
                    v = (v > 20.f) ? v : log1pf(__expf(v));
                    Cz[(size_t)row * ldc + col] = v;
                } else if constexpr (EPI == 2) {
                    Gz[(size_t)row * ldc + col] = f2b(v);             // bf16 partial
                } else if constexpr (EPI == 3) {
                    if (col < DINNER)
                        Cz[(size_t)row * ldc + col] = v;              // xi (f32)
                    else
                        gz[(size_t)row * DINNER + col - DINNER] = f2b(siluf(v));
                } else {
                    Cz[(size_t)row * ldc + col] = v;
                }
            }
}

// sum 16 split-K partials -> xdbl f32 + bf16
__global__ __launch_bounds__(256)
void combine_xdbl(const float* __restrict__ xp, float* __restrict__ xf,
                  unsigned short* __restrict__ xb)
{
    int i = (blockIdx.x * 256 + threadIdx.x) * 4;   // over SEQ*XPWP
    constexpr size_t SL = (size_t)SEQ * XPWP;
    float4 s{0.f, 0.f, 0.f, 0.f};
#pragma unroll
    for (int z = 0; z < 16; ++z) {
        float4 p = *reinterpret_cast<const float4*>(&xp[z * SL + i]);
        s.x += p.x; s.y += p.y; s.z += p.z; s.w += p.w;
    }
    *reinterpret_cast<float4*>(&xf[i]) = s;
    short4_t o; o[0]=(short)f2b(s.x); o[1]=(short)f2b(s.y);
                o[2]=(short)f2b(s.z); o[3]=(short)f2b(s.w);
    *reinterpret_cast<short4_t*>(&xb[i]) = o;
}

// sum 4 bf16 split-K partials -> final f32 out
__global__ __launch_bounds__(256)
void combine_out(const unsigned short* __restrict__ op, float* __restrict__ out)
{
    int i = (blockIdx.x * 256 + threadIdx.x) * 4;   // over SEQ*DMODEL
    constexpr size_t SL = (size_t)SEQ * DMODEL;
    float4 s{0.f, 0.f, 0.f, 0.f};
#pragma unroll
    for (int z = 0; z < 4; ++z) {
        short4_t p = *reinterpret_cast<const short4_t*>(&op[z * SL + i]);
        s.x += b2f((unsigned short)p[0]);
        s.y += b2f((unsigned short)p[1]);
        s.z += b2f((unsigned short)p[2]);
        s.w += b2f((unsigned short)p[3]);
    }
    *reinterpret_cast<float4*>(&out[i]) = s;
}

// causal depthwise conv (width 4) + bias + silu; xi f32 in, xic bf16 out.
__global__ __launch_bounds__(256)
void conv_silu(const float* __restrict__ xi,
               const float* __restrict__ conv_w,
               const float* __restrict__ conv_b,
               unsigned short* __restrict__ xic)
{
    int idx = blockIdx.x * 256 + threadIdx.x;    // over (SEQ/4)*DINNER
    int l0 = (idx / DINNER) * 4;
    int d  = idx % DINNER;
    float4 w = *reinterpret_cast<const float4*>(&conv_w[d * 4]);
    float cb = conv_b[d];
    float v[7];
#pragma unroll
    for (int k = 0; k < 7; ++k) {
        int ls = l0 - 3 + k;
        v[k] = (ls >= 0) ? xi[(size_t)ls * DINNER + d] : 0.f;
    }
#pragma unroll
    for (int j = 0; j < 4; ++j) {
        float acc = cb;
        acc = fmaf(v[j],     w.x, acc);
        acc = fmaf(v[j + 1], w.y, acc);
        acc = fmaf(v[j + 2], w.z, acc);
        acc = fmaf(v[j + 3], w.w, acc);
        xic[(size_t)(l0 + j) * DINNER + d] = f2b(siluf(acc));
    }
}

// ---------------- chunk-parallel selective scan, n-in-registers, barrier-free ----
__global__ __launch_bounds__(256)
void scan_pass1(const float* __restrict__ delta,
                const unsigned short* __restrict__ xic,
                const float* __restrict__ xdbl,     // f32 [SEQ][128], B at 64
                const float* __restrict__ A_log,
                float* __restrict__ sdlbuf,         // [NC][DINNER]
                float* __restrict__ Sbuf, int CH)   // [NC][16][DINNER]
{
    const int tid = threadIdx.x;
    const int d   = blockIdx.x * 256 + tid;
    const int c   = blockIdx.y;
    const int tb  = c * CH;

    float An[16], h[16];
#pragma unroll
    for (int n = 0; n < 16; ++n) {
        An[n] = -__expf(A_log[(size_t)d * 16 + n]);
        h[n]  = 0.f;
    }
    float sdl = 0.f;

#pragma unroll 4
    for (int t = tb; t < tb + CH; ++t) {
        float dl = delta[(size_t)t * DINNER + d];
        float xv = b2f(xic[(size_t)t * DINNER + d]);
        const float4* R = reinterpret_cast<const float4*>(&xdbl[(size_t)t * XPWP + DTRANK]);
        float4 B0 = R[0], B1 = R[1], B2 = R[2], B3 = R[3];
        float Bv[16] = {B0.x,B0.y,B0.z,B0.w, B1.x,B1.y,B1.z,B1.w,
                        B2.x,B2.y,B2.z,B2.w, B3.x,B3.y,B3.z,B3.w};
        float t1 = dl * xv;
        sdl += dl;
#pragma unroll
        for (int n = 0; n < 16; ++n) {
            float a = __expf(dl * An[n]);
            h[n] = fmaf(a, h[n], t1 * Bv[n]);
        }
    }
    sdlbuf[(size_t)c * DINNER + d] = sdl;
#pragma unroll
    for (int n = 0; n < 16; ++n)
        Sbuf[((size_t)c * 16 + n) * DINNER + d] = h[n];
}

// serial scan over chunk summaries; recomputes P = exp(sdl*A); Hin in place over Sbuf
__global__ __launch_bounds__(64)
void scan_pass2(const float* __restrict__ sdlbuf,
                const float* __restrict__ A_log,
                float* __restrict__ Sbuf, int NCr)
{
    int idx = blockIdx.x * 64 + threadIdx.x;        // n*2048 + d
    int n = idx >> 11, d = idx & 2047;
    const float Aneg = -__expf(A_log[(size_t)d * 16 + n]);
    float h = 0.f;
    for (int c = 0; c < NCr; ++c) {
        size_t o = (size_t)c * (DINNER * DSTATE) + idx;
        float p = __expf(sdlbuf[(size_t)c * DINNER + d] * Aneg);
        float s = Sbuf[o];
        Sbuf[o] = h;
        h = fmaf(p, h, s);
    }
}

__global__ __launch_bounds__(256)
void scan_pass3(const float* __restrict__ delta,
                const unsigned short* __restrict__ xic,
                const float* __restrict__ xdbl,     // B at 64, C at 80
                const float* __restrict__ A_log,
                const float* __restrict__ D_skip,
                const unsigned short* __restrict__ gz,   // silu(z) bf16
                const float* __restrict__ Hin,           // [c][n][d] (= Sbuf)
                unsigned short* __restrict__ yfin, int CH)
{
    const int tid = threadIdx.x;
    const int d   = blockIdx.x * 256 + tid;
    const int c   = blockIdx.y;
    const int tb  = c * CH;

    float An[16], h[16];
#pragma unroll
    for (int n = 0; n < 16; ++n) {
        An[n] = -__expf(A_log[(size_t)d * 16 + n]);
        h[n]  = Hin[((size_t)c * 16 + n) * DINNER + d];
    }
    const float Dsk = D_skip[d];

#pragma unroll 4
    for (int t = tb; t < tb + CH; ++t) {
        float dl = delta[(size_t)t * DINNER + d];
        float xv = b2f(xic[(size_t)t * DINNER + d]);
        float zv = b2f(gz[(size_t)t * DINNER + d]);
        const float4* R = reinterpret_cast<const float4*>(&xdbl[(size_t)t * XPWP + DTRANK]);
        float4 B0 = R[0], B1 = R[1], B2 = R[2], B3 = R[3];
        float4 C0 = R[4], C1 = R[5], C2 = R[6], C3 = R[7];
        float Bv[16] = {B0.x,B0.y,B0.z,B0.w, B1.x,B1.y,B1.z,B1.w,
                        B2.x,B2.y,B2.z,B2.w, B3.x,B3.y,B3.z,B3.w};
        float Cv[16] = {C0.x,C0.y,C0.z,C0.w, C1.x,C1.y,C1.z,C1.w,
                        C2.x,C2.y,C2.z,C2.w, C3.x,C3.y,C3.z,C3.w};
        float t1 = dl * xv;
        float y = 0.f;
#pragma unroll
        for (int n = 0; n < 16; ++n) {
            float a = __expf(dl * An[n]);
            h[n] = fmaf(a, h[n], t1 * Bv[n]);
            y = fmaf(h[n], Cv[n], y);
        }
        float yv = fmaf(xv, Dsk, y) * zv;
        yfin[(size_t)t * DINNER + d] = f2b(yv);
    }
}

}  // namespace

extern "C" void kernel_launch(void* const* d_in, const int* in_sizes, int n_in,
                              void* d_out, int out_size, void* d_ws, size_t ws_size,
                              hipStream_t stream)
{
    (void)in_sizes; (void)n_in; (void)out_size;

    const float* x       = (const float*)d_in[0];
    const float* W_in    = (const float*)d_in[1];
    const float* conv_w  = (const float*)d_in[2];
    const float* conv_b  = (const float*)d_in[3];
    const float* W_xproj = (const float*)d_in[4];
    const float* W_dt    = (const float*)d_in[5];
    const float* b_dt    = (const float*)d_in[6];
    const float* A_log   = (const float*)d_in[7];
    const float* D_skip  = (const float*)d_in[8];
    const float* W_out   = (const float*)d_in[9];
    float* out = (float*)d_out;

    // ---- workspace budget / NC select ----
    const size_t F32_FIXED = 2 * (size_t)SEQ * DINNER        // xi_f, delta
                           + (size_t)SEQ * XPWP              // xdbl_f
                           + 16 * (size_t)SEQ * XPWP;        // xpart (16 slabs)
    const size_t BF16_SHORTS = CO5 + 3 * (size_t)SEQ * DINNER + (size_t)SEQ * XPWP
                             + 4 * (size_t)SEQ * DMODEL;     // + opart bf16
    auto need = [&](int nc) {
        return (F32_FIXED + (size_t)nc * DINNER + (size_t)nc * DINNER * DSTATE) * 4
             + BF16_SHORTS * 2;
    };
    int NC = 64;
    if (need(64) > ws_size) NC = 32;
    if (need(32) > ws_size) NC = 16;
    const int CH = SEQ / NC;

    // ---- workspace carve (no aliasing) ----
    float* ws     = (float*)d_ws;
    float* xi_f   = ws;                                    // SEQ*2048
    float* delta  = xi_f   + (size_t)SEQ * DINNER;         // SEQ*2048
    float* xdbl_f = delta  + (size_t)SEQ * DINNER;         // SEQ*128
    float* xpart  = xdbl_f + (size_t)SEQ * XPWP;           // 16*SEQ*128
    float* sdlbuf = xpart  + 16 * (size_t)SEQ * XPWP;      // NC*2048
    float* Sbuf   = sdlbuf + (size_t)NC * DINNER;          // NC*16*2048
    unsigned short* x_b    = (unsigned short*)(Sbuf + (size_t)NC * DINNER * DSTATE);
    unsigned short* Win_b  = x_b + CO1;
    unsigned short* Wxp_b  = x_b + CO2;
    unsigned short* Wdt_b  = x_b + CO3;
    unsigned short* Wout_b = x_b + CO4;
    unsigned short* xic_b  = x_b + CO5;
    unsigned short* yfin_b = xic_b  + (size_t)SEQ * DINNER;
    unsigned short* gz_b   = yfin_b + (size_t)SEQ * DINNER;
    unsigned short* xdbl_b = gz_b   + (size_t)SEQ * DINNER;
    unsigned short* opart_b = xdbl_b + (size_t)SEQ * XPWP;  // 4*SEQ*1024 bf16

    // 0) all bf16 casts
    cast_all<<<(int)((CO5 / 8 + 255) / 256), 256, 0, stream>>>(
        x, W_in, W_xproj, W_dt, W_out, x_b);

    // 1) xz = x @ W_in^T (1024 x 4096, K=1024): 32x16 = 512 blocks
    //    epilogue: cols<2048 -> xi_f (f32), cols>=2048 -> gz = silu(z) bf16
    gemm_mfma<3><<<dim3(512, 1, 1), 256, 0, stream>>>(
        x_b, DMODEL, Win_b, DMODEL, xi_f, DINNER, 0, nullptr, DMODEL, 32, gz_b);

    // 2) conv + silu -> xic (bf16), 4 rows/thread
    conv_silu<<<(SEQ / 4) * DINNER / 256, 256, 0, stream>>>(xi_f, conv_w, conv_b, xic_b);

    // 3) x_dbl = xic @ W_xproj^T, split-K=16 (1024 x 128pad, K=2048): 16 x 16z
    gemm_mfma<0><<<dim3(16, 1, 16), 256, 0, stream>>>(
        xic_b, DINNER, Wxp_b, DINNER, xpart, XPWP, (size_t)SEQ * XPWP,
        nullptr, DINNER / 16, 1, nullptr);
    combine_xdbl<<<(SEQ * XPWP) / 1024, 256, 0, stream>>>(xpart, xdbl_f, xdbl_b);

    // 4) delta = softplus(dt @ W_dt^T + b_dt) (1024 x 2048, K=64): 16x16 = 256 blocks
    gemm_mfma<1><<<dim3(256, 1, 1), 256, 0, stream>>>(
        xdbl_b, XPWP, Wdt_b, DTRANK, delta, DINNER, 0, b_dt, DTRANK, 16, nullptr);

    // 5) chunk-parallel selective scan + gate fusion (barrier-free passes)
    scan_pass1<<<dim3(DINNER / 256, NC), 256, 0, stream>>>(
        delta, xic_b, xdbl_f, A_log, sdlbuf, Sbuf, CH);
    scan_pass2<<<(DINNER * DSTATE) / 64, 64, 0, stream>>>(sdlbuf, A_log, Sbuf, NC);
    scan_pass3<<<dim3(DINNER / 256, NC), 256, 0, stream>>>(
        delta, xic_b, xdbl_f, A_log, D_skip, gz_b, Sbuf, yfin_b, CH);

    // 6) out = y @ W_out^T, split-K=4, bf16 partials (1024 x 1024, K=2048): 512 blocks
    gemm_mfma<2><<<dim3(128, 1, 4), 256, 0, stream>>>(
        yfin_b, DINNER, Wout_b, DINNER, nullptr, DMODEL, (size_t)SEQ * DMODEL,
        nullptr, DINNER / 4, 8, opart_b);
    combine_out<<<(SEQ * DMODEL) / 1024, 256, 0, stream>>>(opart_b, out);
}